// Round 5
// baseline (398.572 us; speedup 1.0000x reference)
//
#include <hip/hip_runtime.h>
#include <stdint.h>

typedef unsigned short u16;
typedef unsigned int u32;
typedef unsigned long long u64;

typedef _Float16 f16x8 __attribute__((ext_vector_type(8)));
typedef __attribute__((ext_vector_type(4))) float f32x4;

// ---------------- workspace layout (bytes) ----------------
#define OFF_SBITS 0u
#define SBITS_BYTES (2048u * 128u * 32u)             // 8 MiB: u64[2048][128][4]
#define OFF_WSWZ (SBITS_BYTES)                       // fp16 2-split, stage-major swizzle:
// stage st = kc*2+s (16 stages x 16 KB). within stage: 16B-slot = j*4 + (q4 ^ ((j>>1)&3)),
// u16 within slot = k&7.  (slot order == DMA lane order == identity)
#define WSWZ_BYTES (16u * 16384u)                    // 256 KiB
#define OFF_CF   (OFF_WSWZ + WSWZ_BYTES)             // float4[256]: W0,W1,W2,K (BN folded)

#define WSCALE 2048.0f
#define INV_WSCALE (1.0f / 2048.0f)

// ---------------- kernel 1: prep (W 2-way fp16 split, swizzled stages) ----
__global__ __launch_bounds__(256) void prep_kernel(
    const float* __restrict__ conv_w, const float* __restrict__ conv_b,
    const float* __restrict__ gamma,  const float* __restrict__ beta,
    const float* __restrict__ mean,   const float* __restrict__ var,
    const float* __restrict__ lin_w,  uint8_t* __restrict__ ws) {
    int tid = threadIdx.x;
    int blk = blockIdx.x;
    if (blk < 256) {
        int j = blk;
        int k = tid;
        float wsc = lin_w[j * 256 + k] * WSCALE;     // exact (x 2^11)
        _Float16 hi = (_Float16)wsc;                 // RN
        float r = wsc - (float)hi;
        _Float16 lo = (_Float16)r;
        union { _Float16 h; u16 u; } ch, cl;
        ch.h = hi; cl.h = lo;
        int kc = k >> 5, q4 = (k >> 3) & 3, k7 = k & 7;
        int c  = q4 ^ ((j >> 1) & 3);                // bank-swizzled 16B slot
        u16* wsw = (u16*)(ws + OFF_WSWZ);
        size_t base = (size_t)(kc * 2) * 8192 + (size_t)(j * 4 + c) * 8 + k7;
        wsw[base]        = ch.u;                     // s = 0 stage
        wsw[base + 8192] = cl.u;                     // s = 1 stage
    } else {
        int h = tid;
        float inv = gamma[h] / sqrtf(var[h] + 1e-5f);
        float K = (conv_b[h] - mean[h]) * inv + beta[h];
        ((float4*)(ws + OFF_CF))[h] = make_float4(conv_w[h * 3 + 0] * inv,
                                                  conv_w[h * 3 + 1] * inv,
                                                  conv_w[h * 3 + 2] * inv, K);
    }
}

// ---------------- kernel 2: encoder (conv+BN+LIF over h, bit-pack spikes) --
__global__ __launch_bounds__(256) void encoder_kernel(
    const float* __restrict__ x,
    const float4* __restrict__ cf,
    u64* __restrict__ sbits) {
    __shared__ float4 cfl[256];
    int tid = threadIdx.x;
    cfl[tid] = cf[tid];

    int p = blockIdx.x * 256 + tid;               // 0..131071
    int c = p & 31;
    int l = (p >> 5) & 127;
    int b0 = p >> 12;                             // 0..31
    int xb = b0 * 4096 + l * 32 + c;
    float xb0 = x[xb],            xb1 = x[xb + 131072];
    float xa0 = (l > 0)   ? x[xb - 32]          : 0.f;
    float xa1 = (l > 0)   ? x[xb + 131072 - 32] : 0.f;
    float xc0 = (l < 127) ? x[xb + 32]          : 0.f;
    float xc1 = (l < 127) ? x[xb + 131072 + 32] : 0.f;
    u64* d0 = sbits + ((size_t)(b0 * 32 + c) * 128 + (size_t)l) * 4;
    u64* d1 = d0 + (size_t)1024 * 512;            // n1 = n0 + 1024

    __syncthreads();
    float v0 = 0.f, v1 = 0.f;
    u64 cur0 = 0ull, cur1 = 0ull;
    #pragma unroll 8
    for (int h = 0; h < 256; ++h) {
        float4 a = cfl[h];
        float e0 = fmaf(a.x, xa0, fmaf(a.y, xb0, fmaf(a.z, xc0, a.w)));
        float e1 = fmaf(a.x, xa1, fmaf(a.y, xb1, fmaf(a.z, xc1, a.w)));
        v0 = v0 + (e0 - v0) * 0.5f;
        v1 = v1 + (e1 - v1) * 0.5f;
        bool s0 = (v0 >= 1.0f);
        bool s1 = (v1 >= 1.0f);
        cur0 |= ((u64)(s0 ? 1u : 0u)) << (h & 63);
        cur1 |= ((u64)(s1 ? 1u : 0u)) << (h & 63);
        if ((h & 63) == 63) {
            d0[h >> 6] = cur0; d1[h >> 6] = cur1;
            cur0 = 0ull; cur1 = 0ull;
        }
        v0 = s0 ? 0.f : v0;
        v1 = s1 ? 0.f : v1;
    }
}

// ---------------- kernel 3: GEMM (binary A bits, 2-split fp16 W) + scan ----
// block = sequence n (2048 blocks). tile 128(t) x 256(j), 4 waves x [128x64].
// 16 pipeline stages (kc,s) of 16 KB, double-buffered, 1 barrier/stage:
//   stage st: issue DMA for st+1 into buf[st&1^1]; (even st) expand A;
//             MFMA 4nf x 8mf from buf[st&1]; __syncthreads.
// LDS: [0,6144) A words 128 x 12 dwords; [6144,38912) B 2 x 16 KB.
// epilogue reuse: Zbuf float[32 t][258 j].
#define AROW 12

__device__ __forceinline__ void gload_lds16(const void* g, void* l) {
    __builtin_amdgcn_global_load_lds(
        (const __attribute__((address_space(1))) u32*)g,
        (__attribute__((address_space(3))) u32*)l, 16, 0, 0);
}

__global__ __launch_bounds__(256, 3) void gemm_scan_kernel(
    const u64* __restrict__ sbits,
    const uint4* __restrict__ wswz,
    const float* __restrict__ lin_b,
    float* __restrict__ out) {
    __shared__ __align__(16) uint8_t smem[38912];
    u32*     Awords = (u32*)smem;
    uint8_t* Bbuf   = smem + 6144;                 // 2 x 16384
    float*   Zbuf   = (float*)smem;

    int tid  = threadIdx.x;
    int n    = blockIdx.x;
    int lane = tid & 63;
    int w    = tid >> 6;
    int l15  = lane & 15;
    int quad = lane >> 4;
    int sq   = quad ^ ((l15 >> 1) & 3);            // bank-swizzled slot sel

    float bias = lin_b[tid];

    // stage A bits: 4 KB into 48 B-padded rows (2-way-free b32 reads)
    {
        const uint4* src = (const uint4*)(sbits + (size_t)n * 512);
        uint4 v = src[tid];
        *(uint4*)(Awords + (tid >> 1) * AROW + (tid & 1) * 4) = v;
    }

    // DMA pipeline stage 0
    #pragma unroll
    for (int ii = 0; ii < 4; ++ii)
        gload_lds16(wswz + ii * 256 + tid,
                    Bbuf + (size_t)(ii * 256 + w * 64) * 16);

    f32x4 acc[8][4];
    #pragma unroll
    for (int mf = 0; mf < 8; ++mf)
        #pragma unroll
        for (int nf = 0; nf < 4; ++nf) {
            f32x4 z = {0.f, 0.f, 0.f, 0.f};
            acc[mf][nf] = z;
        }

    f16x8 afr[8];
    __syncthreads();                               // A bits + stage0 DMA done

    #pragma unroll
    for (int st = 0; st < 16; ++st) {
        const uint8_t* cur = Bbuf + (st & 1) * 16384;
        uint8_t* nxt = Bbuf + ((st & 1) ^ 1) * 16384;
        if (st < 15) {                             // prefetch stage st+1
            const uint4* src = wswz + (size_t)(st + 1) * 1024;
            #pragma unroll
            for (int ii = 0; ii < 4; ++ii)
                gload_lds16(src + ii * 256 + tid,
                            nxt + (size_t)(ii * 256 + w * 64) * 16);
        }
        if ((st & 1) == 0) {                       // expand A for kc = st>>1
            int kc = st >> 1;
            #pragma unroll
            for (int mf = 0; mf < 8; ++mf) {
                u32 word = Awords[(mf * 16 + l15) * AROW + kc];
                u32 b = (word >> (quad * 8)) & 0xFFu;
                u32 s1 = b | (b << 15);
                union { u32 u[4]; f16x8 v; } cv;
                cv.u[0] = ((s1     ) & 0x00010001u) * 0x3C00u;
                cv.u[1] = ((s1 >> 2) & 0x00010001u) * 0x3C00u;
                cv.u[2] = ((s1 >> 4) & 0x00010001u) * 0x3C00u;
                cv.u[3] = ((s1 >> 6) & 0x00010001u) * 0x3C00u;
                afr[mf] = cv.v;
            }
        }
        #pragma unroll
        for (int nf = 0; nf < 4; ++nf) {
            int j = w * 64 + nf * 16 + l15;
            f16x8 bfr = *(const f16x8*)(cur + (size_t)(j * 4 + sq) * 16);
            #pragma unroll
            for (int mf = 0; mf < 8; ++mf)
                acc[mf][nf] = __builtin_amdgcn_mfma_f32_16x16x32_f16(
                    afr[mf], bfr, acc[mf][nf], 0, 0, 0);
        }
        __syncthreads();
    }

    // ---- epilogue: Zbuf [t][j] (32x258) round-trip, fully unrolled ph ----
    // ph MUST be unrolled: dynamic acc[] indexing forces scratch spill (r3).
    float v = 0.f, sOut = 0.f;
    #pragma unroll
    for (int ph = 0; ph < 4; ++ph) {
        #pragma unroll
        for (int mm = 0; mm < 2; ++mm) {
            int mf = ph * 2 + mm;
            #pragma unroll
            for (int nf = 0; nf < 4; ++nf)
                #pragma unroll
                for (int r = 0; r < 4; ++r) {
                    int tl = mm * 16 + quad * 4 + r;           // 0..31
                    int jj = w * 64 + nf * 16 + l15;           // 0..255
                    Zbuf[tl * 258 + jj] = acc[mf][nf][r];
                }
        }
        __syncthreads();
        #pragma unroll
        for (int tl = 0; tl < 32; ++tl) {
            float z = fmaf(Zbuf[tl * 258 + tid], INV_WSCALE, bias);
            v = v + (z - v) * 0.5f;
            bool s = (v >= 1.0f);
            if (ph == 3 && tl == 31) sOut = s ? 1.f : 0.f;
            v = s ? 0.f : v;
        }
        __syncthreads();                           // before next ph overwrite
    }
    out[(size_t)n * 256 + tid]           = sOut;   // (64,1,8192) flat
    out[524288u + (size_t)n * 256 + tid] = sOut;   // (64,8192) flat (identical)
}

// ---------------- launcher ----------------
extern "C" void kernel_launch(void* const* d_in, const int* in_sizes, int n_in,
                              void* d_out, int out_size, void* d_ws, size_t ws_size,
                              hipStream_t stream) {
    const float* x      = (const float*)d_in[0];
    const float* conv_w = (const float*)d_in[1];
    const float* conv_b = (const float*)d_in[2];
    const float* gamma  = (const float*)d_in[3];
    const float* beta   = (const float*)d_in[4];
    const float* mean   = (const float*)d_in[5];
    const float* var    = (const float*)d_in[6];
    const float* lin_w  = (const float*)d_in[7];
    const float* lin_b  = (const float*)d_in[8];
    uint8_t* ws = (uint8_t*)d_ws;
    float* out = (float*)d_out;

    hipLaunchKernelGGL(prep_kernel, dim3(257), dim3(256), 0, stream,
                       conv_w, conv_b, gamma, beta, mean, var, lin_w, ws);
    hipLaunchKernelGGL(encoder_kernel, dim3(512), dim3(256), 0, stream,
                       x, (const float4*)(ws + OFF_CF), (u64*)(ws + OFF_SBITS));
    hipLaunchKernelGGL(gemm_scan_kernel, dim3(2048), dim3(256), 0, stream,
                       (const u64*)(ws + OFF_SBITS),
                       (const uint4*)(ws + OFF_WSWZ), lin_b, out);
}

// Round 6
// 159.314 us; speedup vs baseline: 2.5018x; 2.5018x over previous
//
#include <hip/hip_runtime.h>
#include <stdint.h>

typedef unsigned short u16;
typedef unsigned int u32;
typedef unsigned long long u64;

typedef _Float16 f16x8 __attribute__((ext_vector_type(8)));
typedef __attribute__((ext_vector_type(4))) float f32x4;

// ---------------- workspace layout (bytes) ----------------
#define OFF_SBITS 0u
#define SBITS_BYTES (2048u * 128u * 32u)             // 8 MiB: u64[2048][128][4]
#define OFF_WSWZ (SBITS_BYTES)                       // fp16 2-split, fragment order:
// u16 idx = stage*8192 + j*32 + quad*8 + k7, stage = kc*2+s
// => 16B slot = stage*1024 + j*4 + quad  (lane-contiguous per (stage,nf,wave))
#define WSWZ_BYTES (16u * 16384u)                    // 256 KiB
#define OFF_CF   (OFF_WSWZ + WSWZ_BYTES)             // float4[256]: W0,W1,W2,K (BN folded)

#define WSCALE 2048.0f
#define INV_WSCALE (1.0f / 2048.0f)

// ---------------- kernel 1: prep (W 2-way fp16 split, fragment order) ----
__global__ __launch_bounds__(256) void prep_kernel(
    const float* __restrict__ conv_w, const float* __restrict__ conv_b,
    const float* __restrict__ gamma,  const float* __restrict__ beta,
    const float* __restrict__ mean,   const float* __restrict__ var,
    const float* __restrict__ lin_w,  uint8_t* __restrict__ ws) {
    int tid = threadIdx.x;
    int blk = blockIdx.x;
    if (blk < 256) {
        int j = blk;
        int k = tid;
        float wsc = lin_w[j * 256 + k] * WSCALE;     // exact (x 2^11)
        _Float16 hi = (_Float16)wsc;                 // RN
        float r = wsc - (float)hi;
        _Float16 lo = (_Float16)r;
        union { _Float16 h; u16 u; } ch, cl;
        ch.h = hi; cl.h = lo;
        int kc = k >> 5, q4 = (k >> 3) & 3, k7 = k & 7;
        u16* wsw = (u16*)(ws + OFF_WSWZ);
        size_t base = (size_t)(kc * 2) * 8192 + (size_t)j * 32 + q4 * 8 + k7;
        wsw[base]        = ch.u;                     // stage kc*2   (s=0)
        wsw[base + 8192] = cl.u;                     // stage kc*2+1 (s=1)
    } else {
        int h = tid;
        float inv = gamma[h] / sqrtf(var[h] + 1e-5f);
        float K = (conv_b[h] - mean[h]) * inv + beta[h];
        ((float4*)(ws + OFF_CF))[h] = make_float4(conv_w[h * 3 + 0] * inv,
                                                  conv_w[h * 3 + 1] * inv,
                                                  conv_w[h * 3 + 2] * inv, K);
    }
}

// ---------------- kernel 2: encoder (conv+BN+LIF over h, bit-pack spikes) --
__global__ __launch_bounds__(256) void encoder_kernel(
    const float* __restrict__ x,
    const float4* __restrict__ cf,
    u64* __restrict__ sbits) {
    __shared__ float4 cfl[256];
    int tid = threadIdx.x;
    cfl[tid] = cf[tid];

    int p = blockIdx.x * 256 + tid;               // 0..131071
    int c = p & 31;
    int l = (p >> 5) & 127;
    int b0 = p >> 12;                             // 0..31
    int xb = b0 * 4096 + l * 32 + c;
    float xb0 = x[xb],            xb1 = x[xb + 131072];
    float xa0 = (l > 0)   ? x[xb - 32]          : 0.f;
    float xa1 = (l > 0)   ? x[xb + 131072 - 32] : 0.f;
    float xc0 = (l < 127) ? x[xb + 32]          : 0.f;
    float xc1 = (l < 127) ? x[xb + 131072 + 32] : 0.f;
    u64* d0 = sbits + ((size_t)(b0 * 32 + c) * 128 + (size_t)l) * 4;
    u64* d1 = d0 + (size_t)1024 * 512;            // n1 = n0 + 1024

    __syncthreads();
    float v0 = 0.f, v1 = 0.f;
    u64 cur0 = 0ull, cur1 = 0ull;
    #pragma unroll 8
    for (int h = 0; h < 256; ++h) {
        float4 a = cfl[h];
        float e0 = fmaf(a.x, xa0, fmaf(a.y, xb0, fmaf(a.z, xc0, a.w)));
        float e1 = fmaf(a.x, xa1, fmaf(a.y, xb1, fmaf(a.z, xc1, a.w)));
        v0 = v0 + (e0 - v0) * 0.5f;
        v1 = v1 + (e1 - v1) * 0.5f;
        bool s0 = (v0 >= 1.0f);
        bool s1 = (v1 >= 1.0f);
        cur0 |= ((u64)(s0 ? 1u : 0u)) << (h & 63);
        cur1 |= ((u64)(s1 ? 1u : 0u)) << (h & 63);
        if ((h & 63) == 63) {
            d0[h >> 6] = cur0; d1[h >> 6] = cur1;
            cur0 = 0ull; cur1 = 0ull;
        }
        v0 = s0 ? 0.f : v0;
        v1 = s1 ? 0.f : v1;
    }
}

// ---------------- kernel 3: GEMM (binary A bits, 2-split fp16 W) + scan ----
// block = sequence n (2048 blocks). tile 128(t) x 256(j), 4 waves x [128x64].
// NO LDS for B: waves never share B fragments. Each lane global_load_dwordx4s
// its own fragment from L2-resident W (coalesced 1024 B/instr), register
// double-buffered one kc ahead -> barrier-free K-loop, vmcnt never drains to 0.
// LDS: [0,6144) A words 128 x 12 dwords (K-loop);
//      epilogue reuse: Zbuf float[32 t][258 j] = 33024 B.
#define AROW 12

__global__ __launch_bounds__(256, 2) void gemm_scan_kernel(
    const u64* __restrict__ sbits,
    const uint4* __restrict__ wswz,
    const float* __restrict__ lin_b,
    float* __restrict__ out) {
    __shared__ __align__(16) uint8_t smem[33024];
    u32*   Awords = (u32*)smem;
    float* Zbuf   = (float*)smem;

    int tid  = threadIdx.x;
    int n    = blockIdx.x;
    int lane = tid & 63;
    int w    = tid >> 6;
    int l15  = lane & 15;
    int quad = lane >> 4;
    int lb   = w * 256 + l15 * 4 + quad;           // per-lane W slot base

    const f16x8* Wf = (const f16x8*)wswz;          // 16 B fragment slots

    float bias = lin_b[tid];

    // stage A bits: 4 KB into 48 B-padded rows (2-way/broadcast-free reads)
    {
        const uint4* src = (const uint4*)(sbits + (size_t)n * 512);
        uint4 v = src[tid];
        *(uint4*)(Awords + (tid >> 1) * AROW + (tid & 1) * 4) = v;
    }

    f32x4 acc[8][4];
    #pragma unroll
    for (int mf = 0; mf < 8; ++mf)
        #pragma unroll
        for (int nf = 0; nf < 4; ++nf) {
            f32x4 z = {0.f, 0.f, 0.f, 0.f};
            acc[mf][nf] = z;
        }

    // prologue: load kc=0 B fragments (u = s*4+nf)
    f16x8 bb[2][8];
    #pragma unroll
    for (int u = 0; u < 8; ++u)
        bb[0][u] = Wf[(size_t)((u >> 2) * 1024 + (u & 3) * 64 + lb)];

    __syncthreads();                               // A bits visible

    #pragma unroll
    for (int kc = 0; kc < 8; ++kc) {               // fully unrolled: bb/acc
        int c = kc & 1, nx = c ^ 1;                // indices fold to constants
        if (kc < 7) {                              // prefetch kc+1 (8 loads)
            #pragma unroll
            for (int u = 0; u < 8; ++u)
                bb[nx][u] = Wf[(size_t)(((kc + 1) * 2 + (u >> 2)) * 1024 +
                                        (u & 3) * 64 + lb)];
        }
        // expand A fragments for this kc (VALU, overlaps loads in flight)
        f16x8 afr[8];
        #pragma unroll
        for (int mf = 0; mf < 8; ++mf) {
            u32 word = Awords[(mf * 16 + l15) * AROW + kc];
            u32 b = (word >> (quad * 8)) & 0xFFu;
            u32 s1 = b | (b << 15);
            union { u32 u[4]; f16x8 v; } cv;
            cv.u[0] = ((s1     ) & 0x00010001u) * 0x3C00u;
            cv.u[1] = ((s1 >> 2) & 0x00010001u) * 0x3C00u;
            cv.u[2] = ((s1 >> 4) & 0x00010001u) * 0x3C00u;
            cv.u[3] = ((s1 >> 6) & 0x00010001u) * 0x3C00u;
            afr[mf] = cv.v;
        }
        #pragma unroll
        for (int u = 0; u < 8; ++u) {              // s-major: same acc order
            #pragma unroll
            for (int mf = 0; mf < 8; ++mf)
                acc[mf][u & 3] = __builtin_amdgcn_mfma_f32_16x16x32_f16(
                    afr[mf], bb[c][u], acc[mf][u & 3], 0, 0, 0);
        }
    }

    __syncthreads();                               // last A reads done (alias)

    // ---- epilogue: Zbuf [t][j] (32x258) round-trip, fully unrolled ph ----
    // ph MUST be unrolled: dynamic acc[] indexing forces scratch spill (r3).
    float v = 0.f, sOut = 0.f;
    #pragma unroll
    for (int ph = 0; ph < 4; ++ph) {
        #pragma unroll
        for (int mm = 0; mm < 2; ++mm) {
            int mf = ph * 2 + mm;
            #pragma unroll
            for (int nf = 0; nf < 4; ++nf)
                #pragma unroll
                for (int r = 0; r < 4; ++r) {
                    int tl = mm * 16 + quad * 4 + r;           // 0..31
                    int jj = w * 64 + nf * 16 + l15;           // 0..255
                    Zbuf[tl * 258 + jj] = acc[mf][nf][r];
                }
        }
        __syncthreads();
        #pragma unroll
        for (int tl = 0; tl < 32; ++tl) {
            float z = fmaf(Zbuf[tl * 258 + tid], INV_WSCALE, bias);
            v = v + (z - v) * 0.5f;
            bool s = (v >= 1.0f);
            if (ph == 3 && tl == 31) sOut = s ? 1.f : 0.f;
            v = s ? 0.f : v;
        }
        __syncthreads();                           // before next ph overwrite
    }
    out[(size_t)n * 256 + tid]           = sOut;   // (64,1,8192) flat
    out[524288u + (size_t)n * 256 + tid] = sOut;   // (64,8192) flat (identical)
}

// ---------------- launcher ----------------
extern "C" void kernel_launch(void* const* d_in, const int* in_sizes, int n_in,
                              void* d_out, int out_size, void* d_ws, size_t ws_size,
                              hipStream_t stream) {
    const float* x      = (const float*)d_in[0];
    const float* conv_w = (const float*)d_in[1];
    const float* conv_b = (const float*)d_in[2];
    const float* gamma  = (const float*)d_in[3];
    const float* beta   = (const float*)d_in[4];
    const float* mean   = (const float*)d_in[5];
    const float* var    = (const float*)d_in[6];
    const float* lin_w  = (const float*)d_in[7];
    const float* lin_b  = (const float*)d_in[8];
    uint8_t* ws = (uint8_t*)d_ws;
    float* out = (float*)d_out;

    hipLaunchKernelGGL(prep_kernel, dim3(257), dim3(256), 0, stream,
                       conv_w, conv_b, gamma, beta, mean, var, lin_w, ws);
    hipLaunchKernelGGL(encoder_kernel, dim3(512), dim3(256), 0, stream,
                       x, (const float4*)(ws + OFF_CF), (u64*)(ws + OFF_SBITS));
    hipLaunchKernelGGL(gemm_scan_kernel, dim3(2048), dim3(256), 0, stream,
                       (const u64*)(ws + OFF_SBITS),
                       (const uint4*)(ws + OFF_WSWZ), lin_b, out);
}

// Round 7
// 157.586 us; speedup vs baseline: 2.5292x; 1.0110x over previous
//
#include <hip/hip_runtime.h>
#include <stdint.h>

typedef unsigned short u16;
typedef unsigned int u32;
typedef unsigned long long u64;

typedef _Float16 f16x8 __attribute__((ext_vector_type(8)));
typedef __attribute__((ext_vector_type(4))) float f32x4;

// ---------------- workspace layout (bytes) ----------------
#define OFF_SBITS 0u
#define SBITS_BYTES (2048u * 128u * 32u)             // 8 MiB: u64[2048][128][4]
#define OFF_WSWZ (SBITS_BYTES)                       // fp16 2-split, fragment order:
// u16 idx = stage*8192 + j*32 + quad*8 + k7, stage = kc*2+s
// => 16B slot = stage*1024 + j*4 + quad  (lane-contiguous per (stage,nf,wave))
#define WSWZ_BYTES (16u * 16384u)                    // 256 KiB
#define OFF_CF   (OFF_WSWZ + WSWZ_BYTES)             // float4[256]: W0,W1,W2,K (BN folded)

#define WSCALE 2048.0f
#define INV_WSCALE (1.0f / 2048.0f)

// ---------------- kernel 1: prep (W 2-way fp16 split, fragment order) ----
__global__ __launch_bounds__(256) void prep_kernel(
    const float* __restrict__ conv_w, const float* __restrict__ conv_b,
    const float* __restrict__ gamma,  const float* __restrict__ beta,
    const float* __restrict__ mean,   const float* __restrict__ var,
    const float* __restrict__ lin_w,  uint8_t* __restrict__ ws) {
    int tid = threadIdx.x;
    int blk = blockIdx.x;
    if (blk < 256) {
        int j = blk;
        int k = tid;
        float wsc = lin_w[j * 256 + k] * WSCALE;     // exact (x 2^11)
        _Float16 hi = (_Float16)wsc;                 // RN
        float r = wsc - (float)hi;
        _Float16 lo = (_Float16)r;
        union { _Float16 h; u16 u; } ch, cl;
        ch.h = hi; cl.h = lo;
        int kc = k >> 5, q4 = (k >> 3) & 3, k7 = k & 7;
        u16* wsw = (u16*)(ws + OFF_WSWZ);
        size_t base = (size_t)(kc * 2) * 8192 + (size_t)j * 32 + q4 * 8 + k7;
        wsw[base]        = ch.u;                     // stage kc*2   (s=0)
        wsw[base + 8192] = cl.u;                     // stage kc*2+1 (s=1)
    } else {
        int h = tid;
        float inv = gamma[h] / sqrtf(var[h] + 1e-5f);
        float K = (conv_b[h] - mean[h]) * inv + beta[h];
        ((float4*)(ws + OFF_CF))[h] = make_float4(conv_w[h * 3 + 0] * inv,
                                                  conv_w[h * 3 + 1] * inv,
                                                  conv_w[h * 3 + 2] * inv, K);
    }
}

// ---------------- kernel 2: encoder (conv+BN+LIF over h, bit-pack spikes) --
__global__ __launch_bounds__(256) void encoder_kernel(
    const float* __restrict__ x,
    const float4* __restrict__ cf,
    u64* __restrict__ sbits) {
    __shared__ float4 cfl[256];
    int tid = threadIdx.x;
    cfl[tid] = cf[tid];

    int p = blockIdx.x * 256 + tid;               // 0..131071
    int c = p & 31;
    int l = (p >> 5) & 127;
    int b0 = p >> 12;                             // 0..31
    int xb = b0 * 4096 + l * 32 + c;
    float xb0 = x[xb],            xb1 = x[xb + 131072];
    float xa0 = (l > 0)   ? x[xb - 32]          : 0.f;
    float xa1 = (l > 0)   ? x[xb + 131072 - 32] : 0.f;
    float xc0 = (l < 127) ? x[xb + 32]          : 0.f;
    float xc1 = (l < 127) ? x[xb + 131072 + 32] : 0.f;
    u64* d0 = sbits + ((size_t)(b0 * 32 + c) * 128 + (size_t)l) * 4;
    u64* d1 = d0 + (size_t)1024 * 512;            // n1 = n0 + 1024

    __syncthreads();
    float v0 = 0.f, v1 = 0.f;
    u64 cur0 = 0ull, cur1 = 0ull;
    #pragma unroll 8
    for (int h = 0; h < 256; ++h) {
        float4 a = cfl[h];
        float e0 = fmaf(a.x, xa0, fmaf(a.y, xb0, fmaf(a.z, xc0, a.w)));
        float e1 = fmaf(a.x, xa1, fmaf(a.y, xb1, fmaf(a.z, xc1, a.w)));
        v0 = v0 + (e0 - v0) * 0.5f;
        v1 = v1 + (e1 - v1) * 0.5f;
        bool s0 = (v0 >= 1.0f);
        bool s1 = (v1 >= 1.0f);
        cur0 |= ((u64)(s0 ? 1u : 0u)) << (h & 63);
        cur1 |= ((u64)(s1 ? 1u : 0u)) << (h & 63);
        if ((h & 63) == 63) {
            d0[h >> 6] = cur0; d1[h >> 6] = cur1;
            cur0 = 0ull; cur1 = 0ull;
        }
        v0 = s0 ? 0.f : v0;
        v1 = s1 ? 0.f : v1;
    }
}

// ---------------- kernel 3: GEMM (binary A bits, 2-split fp16 W) + scan ----
// block = sequence n (2048 blocks). tile 128(t) x 256(j), 4 waves x [128x64].
// K-loop (r6, unchanged): no LDS for B — each lane global_load_dwordx4s its
// fragment from L2-resident W, register double-buffered; barrier-free.
// Epilogue (NEW): wave-private Zbuf slice 32t x 68j (each wave's acc holds
// ALL 128 t for its own 64 j) -> zero epilogue barriers; reads batched into
// zv[32] regs so LDS latency is paid once per phase, not per scan step.
// LDS: [0,6144) A words (K-loop) | epilogue: 4 waves x 8704 B slices.
#define AROW 12

__global__ __launch_bounds__(256, 2) void gemm_scan_kernel(
    const u64* __restrict__ sbits,
    const uint4* __restrict__ wswz,
    const float* __restrict__ lin_b,
    float* __restrict__ out) {
    __shared__ __align__(16) uint8_t smem[34816];
    u32* Awords = (u32*)smem;

    int tid  = threadIdx.x;
    int n    = blockIdx.x;
    int lane = tid & 63;
    int w    = tid >> 6;
    int l15  = lane & 15;
    int quad = lane >> 4;
    int lb   = w * 256 + l15 * 4 + quad;           // per-lane W slot base

    const f16x8* Wf = (const f16x8*)wswz;          // 16 B fragment slots

    float bias = lin_b[tid];

    // stage A bits: 4 KB into 48 B-padded rows (2-way/broadcast-free reads)
    {
        const uint4* src = (const uint4*)(sbits + (size_t)n * 512);
        uint4 v = src[tid];
        *(uint4*)(Awords + (tid >> 1) * AROW + (tid & 1) * 4) = v;
    }

    f32x4 acc[8][4];
    #pragma unroll
    for (int mf = 0; mf < 8; ++mf)
        #pragma unroll
        for (int nf = 0; nf < 4; ++nf) {
            f32x4 z = {0.f, 0.f, 0.f, 0.f};
            acc[mf][nf] = z;
        }

    // prologue: load kc=0 B fragments (u = s*4+nf)
    f16x8 bb[2][8];
    #pragma unroll
    for (int u = 0; u < 8; ++u)
        bb[0][u] = Wf[(size_t)((u >> 2) * 1024 + (u & 3) * 64 + lb)];

    __syncthreads();                               // A bits visible

    #pragma unroll
    for (int kc = 0; kc < 8; ++kc) {               // fully unrolled: bb/acc
        int c = kc & 1, nx = c ^ 1;                // indices fold to constants
        if (kc < 7) {                              // prefetch kc+1 (8 loads)
            #pragma unroll
            for (int u = 0; u < 8; ++u)
                bb[nx][u] = Wf[(size_t)(((kc + 1) * 2 + (u >> 2)) * 1024 +
                                        (u & 3) * 64 + lb)];
        }
        // expand A fragments for this kc (VALU, overlaps loads in flight)
        f16x8 afr[8];
        #pragma unroll
        for (int mf = 0; mf < 8; ++mf) {
            u32 word = Awords[(mf * 16 + l15) * AROW + kc];
            u32 b = (word >> (quad * 8)) & 0xFFu;
            u32 s1 = b | (b << 15);
            union { u32 u[4]; f16x8 v; } cv;
            cv.u[0] = ((s1     ) & 0x00010001u) * 0x3C00u;
            cv.u[1] = ((s1 >> 2) & 0x00010001u) * 0x3C00u;
            cv.u[2] = ((s1 >> 4) & 0x00010001u) * 0x3C00u;
            cv.u[3] = ((s1 >> 6) & 0x00010001u) * 0x3C00u;
            afr[mf] = cv.v;
        }
        #pragma unroll
        for (int u = 0; u < 8; ++u) {              // s-major: same acc order
            #pragma unroll
            for (int mf = 0; mf < 8; ++mf)
                acc[mf][u & 3] = __builtin_amdgcn_mfma_f32_16x16x32_f16(
                    afr[mf], bb[c][u], acc[mf][u & 3], 0, 0, 0);
        }
    }

    __syncthreads();   // all waves done with A region before Zbuf overlays it

    // ---- epilogue: wave-private Zbuf 32t x 68j, barrier-free LIF scan ----
    // wave w owns j in [64w, 64w+64): acc nf covers its j, mf covers all t.
    // Same-wave DS ops are in-order -> no __syncthreads needed.
    float* ZW = (float*)(smem + (size_t)w * 8704);   // 32*68 floats
    float v = 0.f, sOut = 0.f;
    #pragma unroll
    for (int ph = 0; ph < 4; ++ph) {
        #pragma unroll
        for (int mm = 0; mm < 2; ++mm) {
            int mf = ph * 2 + mm;
            #pragma unroll
            for (int nf = 0; nf < 4; ++nf)
                #pragma unroll
                for (int r = 0; r < 4; ++r) {
                    int tl = mm * 16 + quad * 4 + r;           // 0..31
                    int jl = nf * 16 + l15;                    // 0..63
                    ZW[tl * 68 + jl] = acc[mf][nf][r];
                }
        }
        // batch all 32 reads first: one LDS latency exposure per phase
        float zv[32];
        #pragma unroll
        for (int tl = 0; tl < 32; ++tl)
            zv[tl] = ZW[tl * 68 + lane];
        #pragma unroll
        for (int tl = 0; tl < 32; ++tl) {
            float z = fmaf(zv[tl], INV_WSCALE, bias);
            v = v + (z - v) * 0.5f;
            bool s = (v >= 1.0f);
            if (ph == 3 && tl == 31) sOut = s ? 1.f : 0.f;
            v = s ? 0.f : v;
        }
    }
    out[(size_t)n * 256 + tid]           = sOut;   // (64,1,8192) flat
    out[524288u + (size_t)n * 256 + tid] = sOut;   // (64,8192) flat (identical)
}

// ---------------- launcher ----------------
extern "C" void kernel_launch(void* const* d_in, const int* in_sizes, int n_in,
                              void* d_out, int out_size, void* d_ws, size_t ws_size,
                              hipStream_t stream) {
    const float* x      = (const float*)d_in[0];
    const float* conv_w = (const float*)d_in[1];
    const float* conv_b = (const float*)d_in[2];
    const float* gamma  = (const float*)d_in[3];
    const float* beta   = (const float*)d_in[4];
    const float* mean   = (const float*)d_in[5];
    const float* var    = (const float*)d_in[6];
    const float* lin_w  = (const float*)d_in[7];
    const float* lin_b  = (const float*)d_in[8];
    uint8_t* ws = (uint8_t*)d_ws;
    float* out = (float*)d_out;

    hipLaunchKernelGGL(prep_kernel, dim3(257), dim3(256), 0, stream,
                       conv_w, conv_b, gamma, beta, mean, var, lin_w, ws);
    hipLaunchKernelGGL(encoder_kernel, dim3(512), dim3(256), 0, stream,
                       x, (const float4*)(ws + OFF_CF), (u64*)(ws + OFF_SBITS));
    hipLaunchKernelGGL(gemm_scan_kernel, dim3(2048), dim3(256), 0, stream,
                       (const u64*)(ws + OFF_SBITS),
                       (const uint4*)(ws + OFF_WSWZ), lin_b, out);
}